// Round 6
// baseline (985.823 us; speedup 1.0000x reference)
//
#include <hip/hip_runtime.h>
#include <float.h>
#include <limits.h>

#define N_Q 8192
#define M_PTS 50000
#define DIM 128
#define KNN 10
#define NCLS 10
#define NCHUNK 32          // R5: 32 chunks x 98 tiles (was 16x196) -> 2048 blocks, 8/CU
#define TPC 98             // tiles per chunk (uniform, compile-time)
#define CPC 8              // candidates kept per (query, chunk)
#define NCAND (NCHUNK*CPC) // 256 candidates per query (superset of proven 128)
#define NSEL 48            // rescored candidates: 48/256 == proven ratio 24/128
#define TPL 4              // per-lane-class top depth (98 keys/class now: safer)
#define QPB 128            // queries per block (4 waves x 32)
#define SBIAS 256.0f       // pre-added to y2: keys positive -> u32 order == float order
#define XN4 (N_Q*DIM/4)    // 262144 float4 in x
#define YN4 (M_PTS*DIM/4)  // 1600000 float4 in y

typedef __attribute__((ext_vector_type(8))) int i32x8;
typedef __attribute__((ext_vector_type(4))) float f32x4;
typedef unsigned int u32;

// ---------------------------------------------------------------------------
// fp32 -> e4m3 via the HW packed converter.
// ---------------------------------------------------------------------------
__device__ __forceinline__ u32 pack4_e4m3(float4 v, float sc) {
    u32 w = 0;
    w = __builtin_amdgcn_cvt_pk_fp8_f32(sc * v.x, sc * v.y, w, false);
    w = __builtin_amdgcn_cvt_pk_fp8_f32(sc * v.z, sc * v.w, w, true);
    return w;
}

// ---------------------------------------------------------------------------
// Prep (coalesced reads): xb8 = e4m3(-2x) row-major; yt8 = e4m3(y) tile
// records (2 KB/tile, global tile id, slot l = g*16+nr); y2 = ||y||^2+SBIAS;
// pads 50000..50175 = FLT_MAX. Unchanged: chunk partition is a pure re-index.
// ---------------------------------------------------------------------------
__global__ __launch_bounds__(256) void prep_kernel(
    const float4* __restrict__ x4, const float4* __restrict__ y4,
    u32* __restrict__ xb8, u32* __restrict__ yt8, float* __restrict__ y2) {
    int t = blockIdx.x * 256 + threadIdx.x;
    if (t < XN4) {
        xb8[t] = pack4_e4m3(x4[t], -2.0f);  // row-major: u32 idx == t
    } else if (t < XN4 + YN4) {
        int j = t - XN4;                    // float4 index into y
        int row = j >> 5;                   // point 0..49999
        int d4  = j & 31;                   // which float4 of the row
        float4 v = y4[j];
        u32 w = pack4_e4m3(v, 1.0f);
        int T = row >> 4, nr = row & 15;
        int g2 = d4 >> 3, s = d4 & 7;
        yt8[(size_t)T * 512 + (g2 * 16 + nr) * 8 + s] = w;
        float p = v.x * v.x + v.y * v.y + v.z * v.z + v.w * v.w;
        #pragma unroll
        for (int off = 16; off > 0; off >>= 1) p += __shfl_xor(p, off, 64);
        if (d4 == 0) y2[row] = p + SBIAS;
    } else if (t < XN4 + YN4 + 176) {
        y2[M_PTS + (t - XN4 - YN4)] = FLT_MAX;   // pad tiles: never selected
    }
}

// ---------------------------------------------------------------------------
// Filter: fp8 e4m3 16x16x128 scaled-MFMA (unit scales), TWO query-sets per
// wave, C = y2+SBIAS splat, per-lane-class top-4 via min+3 med3 (5 VALU/score
// = proven instruction floor, R10-R15 law: wall ~3.35us per M wave-VALU).
// R5: occupancy attack. Grid 32x64 = 2048 blocks; LDS cut to 16.6 KB via
// two-pass merge -> 8 blocks/CU, 8 waves/SIMD (was 4; VALUBusy 75% showed
// ~25% uncovered MFMA/load latency). Inner loop byte-identical to proven.
// ---------------------------------------------------------------------------
__global__ __launch_bounds__(256, 8) void knn_filter(
    const u32* __restrict__ xb8, const u32* __restrict__ yt8,
    const float* __restrict__ y2, u32* __restrict__ ckey) {
    const int lane = threadIdx.x & 63;
    const int wid  = threadIdx.x >> 6;      // wave 0..3
    const int g    = lane >> 4;             // k-group 0..3
    const int nrow = lane & 15;             // point-in-tile (B col / C col)
    const int chunk = blockIdx.x;           // 0..31
    const int qb    = blockIdx.y;
    const int qw = qb * QPB + wid * 32;

    // A fragments: 2 query-sets, 8 dwords each (32 fp8 = k-slice 32g..32g+31)
    i32x8 a[2];
    #pragma unroll
    for (int s = 0; s < 2; ++s)
        a[s] = *(const i32x8*)(xb8 + (size_t)(qw + s * 16 + nrow) * 32 + g * 8);

    float ts[8][TPL];
    #pragma unroll
    for (int r = 0; r < 8; ++r)
        #pragma unroll
        for (int l = 0; l < TPL; ++l) ts[r][l] = FLT_MAX;

    const u32* ytp = yt8 + (size_t)chunk * TPC * 512 + lane * 8;
    const float* y2p = y2 + chunk * TPC * 16 + nrow;

    // prefetch tile 0 (R4: measured neutral, kept -- zero cost)
    i32x8 b = *(const i32x8*)(ytp);
    float y2n = y2p[0];

    #pragma unroll 2
    for (int t = 0; t < TPC; ++t) {
        int tn = (t + 1 < TPC) ? t + 1 : t;
        i32x8 bn = *(const i32x8*)(ytp + (size_t)tn * 512);
        float y2nn = y2p[tn * 16];

        f32x4 cq = {y2n, y2n, y2n, y2n};    // y2+SBIAS pre-loaded into C
        f32x4 d0 = __builtin_amdgcn_mfma_scale_f32_16x16x128_f8f6f4(
            a[0], b, cq, 0, 0, 0, 0x7F7F7F7F, 0, 0x7F7F7F7F);
        f32x4 d1 = __builtin_amdgcn_mfma_scale_f32_16x16x128_f8f6f4(
            a[1], b, cq, 0, 0, 0, 0x7F7F7F7F, 0, 0x7F7F7F7F);
        u32 rel = (u32)(t * 16) | (u32)nrow;          // < 1568, 12 bits
        #pragma unroll
        for (int i = 0; i < 4; ++i) {
            float key = __uint_as_float((__float_as_uint(d0[i]) & 0xFFFFF000u) | rel);
            float o0 = ts[i][0], o1 = ts[i][1], o2 = ts[i][2];
            ts[i][0] = fminf(o0, key);
            ts[i][1] = __builtin_amdgcn_fmed3f(key, o0, o1);
            ts[i][2] = __builtin_amdgcn_fmed3f(key, o1, o2);
            ts[i][3] = __builtin_amdgcn_fmed3f(key, o2, ts[i][3]);
        }
        #pragma unroll
        for (int i = 0; i < 4; ++i) {
            float key = __uint_as_float((__float_as_uint(d1[i]) & 0xFFFFF000u) | rel);
            float o0 = ts[4 + i][0], o1 = ts[4 + i][1], o2 = ts[4 + i][2];
            ts[4 + i][0] = fminf(o0, key);
            ts[4 + i][1] = __builtin_amdgcn_fmed3f(key, o0, o1);
            ts[4 + i][2] = __builtin_amdgcn_fmed3f(key, o1, o2);
            ts[4 + i][3] = __builtin_amdgcn_fmed3f(key, o2, ts[4 + i][3]);
        }
        b = bn;
        y2n = y2nn;
    }

    // ---- merge 16 lane-classes -> per-query sorted top-8, TWO PASSES ----
    // (pass s handles query-set s of every wave: 64 queries; LDS = 16.6 KB
    //  so 8 blocks/CU fit. Stream ts[s*4+r] on lane(g,nrow) of wave wid is
    //  query qb*128 + wid*32 + s*16 + g*4+r, class nrow.)
    __shared__ u32 smem[64 * 65];           // 16640 B
    #pragma unroll
    for (int s = 0; s < 2; ++s) {
        if (s) __syncthreads();             // pass-0 reads done before reuse
        #pragma unroll
        for (int r = 0; r < 4; ++r) {
            int qh = wid * 16 + g * 4 + r;  // 0..63
            #pragma unroll
            for (int l = 0; l < TPL; ++l)
                smem[qh * 65 + nrow * TPL + l] = __float_as_uint(ts[s * 4 + r][l]);
        }
        __syncthreads();
        if (threadIdx.x < 64) {
            int qh = threadIdx.x;
            float bs[CPC];
            #pragma unroll
            for (int i = 0; i < CPC; ++i) bs[i] = FLT_MAX;
            for (int e = 0; e < 16 * TPL; ++e) {   // stride-65: conflict-free
                float f = __uint_as_float(smem[qh * 65 + e]);
                #pragma unroll
                for (int q2 = 0; q2 < CPC; ++q2) {
                    float mn = fminf(bs[q2], f);
                    f = fmaxf(bs[q2], f);
                    bs[q2] = mn;
                }
            }
            int gq = qb * QPB + (qh >> 4) * 32 + s * 16 + (qh & 15);
            u32* dst = ckey + ((size_t)gq * NCHUNK + chunk) * CPC;
            #pragma unroll
            for (int i = 0; i < CPC; ++i) dst[i] = __float_as_uint(bs[i]);
        }
    }
}

// ---------------------------------------------------------------------------
// Finalize: 8 queries/block, half-wave per query. R5: NCAND 256, NSEL 48.
//  1. parallel exact-rank select of approx-top-48 from 256 keys (u32 compare
//     valid: keys positive via SBIAS; position tie-break -> unique ranks).
//  2. exact fp64 rescore, coalesced: half-wave does one candidate at a time,
//     32 lanes x float4 = 512B coalesced row load + butterfly reduce.
//  3. parallel top-10: each sub-lane ranks its (<=2) candidates among the 48
//     by (score,idx); rank<10 -> write LABEL. Ties -> LARGEST label.
// ---------------------------------------------------------------------------
__global__ __launch_bounds__(256) void knn_finalize(
    const u32* __restrict__ ckey, const float* __restrict__ x,
    const float* __restrict__ y, const int* __restrict__ labels,
    int* __restrict__ out) {
    const int lane = threadIdx.x & 63;
    const int wid  = threadIdx.x >> 6;
    const int qbase = blockIdx.x * 8;
    const int ql = wid * 2 + (lane >> 5);   // query-in-block 0..7
    const int sl = lane & 31;               // sub-lane in half-wave

    __shared__ u32 skey[8][NCAND];          // 8 KB
    __shared__ int sidx[8][NSEL];
    __shared__ double sex[8][NSEL];
    __shared__ int slab[8][KNN];

    for (int i = threadIdx.x; i < 8 * NCAND; i += 256)
        skey[i >> 8][i & 255] = ckey[(size_t)(qbase + (i >> 8)) * NCAND + (i & 255)];
    __syncthreads();

    // 1. parallel rank select: 8 candidates per sub-lane, one kj read per j
    {
        u32 ke[8];
        int rank[8];
        #pragma unroll
        for (int r0 = 0; r0 < 8; ++r0) {
            ke[r0] = skey[ql][r0 * 32 + sl];
            rank[r0] = 0;
        }
        for (int j = 0; j < NCAND; ++j) {
            u32 kj = skey[ql][j];
            #pragma unroll
            for (int r0 = 0; r0 < 8; ++r0)
                rank[r0] += (kj < ke[r0] || (kj == ke[r0] && j < r0 * 32 + sl)) ? 1 : 0;
        }
        #pragma unroll
        for (int r0 = 0; r0 < 8; ++r0) {
            if (rank[r0] < NSEL) {
                int e = r0 * 32 + sl;
                sidx[ql][rank[r0]] = (e >> 3) * (TPC * 16) + (int)(ke[r0] & 0xFFFu);
            }
        }
    }
    __syncthreads();

    // 2. exact fp64 rescore, coalesced per-candidate (half-wave cooperative)
    {
        const float4* xr = (const float4*)(x + (size_t)(qbase + ql) * DIM);
        float4 xv = xr[sl];                 // query row staged once, coalesced
        for (int c = 0; c < NSEL; ++c) {
            int idx = sidx[ql][c];          // LDS broadcast (uniform per half)
            const float4* yr = (const float4*)(y + (size_t)idx * DIM);
            float4 yv = yr[sl];             // 32 lanes x 16B = 512B coalesced
            double dy = 0.0, dx = 0.0;
            dy = fma((double)yv.x, (double)yv.x, dy);
            dy = fma((double)yv.y, (double)yv.y, dy);
            dy = fma((double)yv.z, (double)yv.z, dy);
            dy = fma((double)yv.w, (double)yv.w, dy);
            dx = fma((double)xv.x, (double)yv.x, dx);
            dx = fma((double)xv.y, (double)yv.y, dx);
            dx = fma((double)xv.z, (double)yv.z, dx);
            dx = fma((double)xv.w, (double)yv.w, dx);
            double part = fma(-2.0, dx, dy);
            #pragma unroll
            for (int off = 16; off > 0; off >>= 1)
                part += __shfl_xor(part, off, 64);   // stays within 32-half
            if (sl == 0) sex[ql][c] = part;
        }
    }
    __syncthreads();

    // 3. parallel top-10: rank candidates among the 48 by (score, idx)
    for (int c = sl; c < NSEL; c += 32) {
        int mi = sidx[ql][c];
        double s = sex[ql][c];
        int cnt = 0;
        #pragma unroll
        for (int j = 0; j < NSEL; ++j) {
            double sj = sex[ql][j];
            cnt += (sj < s || (sj == s && sidx[ql][j] < mi)) ? 1 : 0;
        }
        if (cnt < KNN) slab[ql][cnt] = labels[mi];
    }
    __syncthreads();

    if (sl == 0) {
        int lab[KNN];
        #pragma unroll
        for (int i = 0; i < KNN; ++i) lab[i] = slab[ql][i];
        int bestc = 0, bestn = -1;
        #pragma unroll
        for (int c = 0; c < NCLS; ++c) {
            int n = 0;
            #pragma unroll
            for (int i = 0; i < KNN; ++i) n += (lab[i] == c) ? 1 : 0;
            if (n >= bestn) { bestn = n; bestc = c; }   // >= : ties -> larger label
        }
        out[qbase + ql] = bestc;
    }
}

// ---------------------------------------------------------------------------
extern "C" void kernel_launch(void* const* d_in, const int* in_sizes, int n_in,
                              void* d_out, int out_size, void* d_ws, size_t ws_size,
                              hipStream_t stream) {
    const float* x      = (const float*)d_in[0];
    const float* y      = (const float*)d_in[1];
    const int*   labels = (const int*)d_in[2];
    // d_in[3] is k == 10, baked in.

    char* ws = (char*)d_ws;
    size_t off = 0;
    u32* xb8 = (u32*)(ws + off);    off += (size_t)N_Q * DIM;            //  1.05 MB
    u32* yt8 = (u32*)(ws + off);    off += (size_t)NCHUNK * TPC * 2048;  //  6.42 MB
    float* y2 = (float*)(ws + off); off += (size_t)NCHUNK * TPC * 16 * 4;//  0.20 MB
    u32* ckey = (u32*)(ws + off);   off += (size_t)N_Q * NCAND * 4;      //  8.39 MB
    int* out = (int*)d_out;

    prep_kernel<<<(XN4 + YN4 + 176 + 255) / 256, 256, 0, stream>>>(
        (const float4*)x, (const float4*)y, xb8, yt8, y2);
    knn_filter<<<dim3(NCHUNK, N_Q / QPB), 256, 0, stream>>>(xb8, yt8, y2, ckey);
    knn_finalize<<<N_Q / 8, 256, 0, stream>>>(ckey, x, y, labels, out);
}

// Round 8
// 335.266 us; speedup vs baseline: 2.9404x; 2.9404x over previous
//
#include <hip/hip_runtime.h>
#include <float.h>
#include <limits.h>

#define N_Q 8192
#define M_PTS 50000
#define DIM 128
#define KNN 10
#define NCLS 10
#define NCHUNK 32          // 32 chunks x 98 tiles -> grid 2048 = 8 blocks/CU available
#define TPC 98             // tiles per chunk (uniform, compile-time)
#define CPC 8              // candidates kept per (query, chunk)
#define NCAND (NCHUNK*CPC) // 256 candidates per query (superset of proven 128)
#define NSEL 48            // rescored candidates: 48/256 == proven ratio 24/128
#define TPL 4              // per-lane-class top depth (98 keys/class: safe)
#define QPB 128            // queries per block (4 waves x 32)
#define SBIAS 256.0f       // pre-added to y2: keys positive -> u32 order == float order
#define XN4 (N_Q*DIM/4)    // 262144 float4 in x
#define YN4 (M_PTS*DIM/4)  // 1600000 float4 in y

typedef __attribute__((ext_vector_type(8))) int i32x8;
typedef __attribute__((ext_vector_type(4))) float f32x4;
typedef unsigned int u32;

// ---------------------------------------------------------------------------
// fp32 -> e4m3 via the HW packed converter.
// ---------------------------------------------------------------------------
__device__ __forceinline__ u32 pack4_e4m3(float4 v, float sc) {
    u32 w = 0;
    w = __builtin_amdgcn_cvt_pk_fp8_f32(sc * v.x, sc * v.y, w, false);
    w = __builtin_amdgcn_cvt_pk_fp8_f32(sc * v.z, sc * v.w, w, true);
    return w;
}

// ---------------------------------------------------------------------------
// Prep (coalesced reads): xb8 = e4m3(-2x) row-major; yt8 = e4m3(y) tile
// records (2 KB/tile, global tile id, slot l = g*16+nr); y2 = ||y||^2+SBIAS;
// pads 50000..50175 = FLT_MAX. Chunk partition is a pure re-index.
// ---------------------------------------------------------------------------
__global__ __launch_bounds__(256) void prep_kernel(
    const float4* __restrict__ x4, const float4* __restrict__ y4,
    u32* __restrict__ xb8, u32* __restrict__ yt8, float* __restrict__ y2) {
    int t = blockIdx.x * 256 + threadIdx.x;
    if (t < XN4) {
        xb8[t] = pack4_e4m3(x4[t], -2.0f);  // row-major: u32 idx == t
    } else if (t < XN4 + YN4) {
        int j = t - XN4;                    // float4 index into y
        int row = j >> 5;                   // point 0..49999
        int d4  = j & 31;                   // which float4 of the row
        float4 v = y4[j];
        u32 w = pack4_e4m3(v, 1.0f);
        int T = row >> 4, nr = row & 15;
        int g2 = d4 >> 3, s = d4 & 7;
        yt8[(size_t)T * 512 + (g2 * 16 + nr) * 8 + s] = w;
        float p = v.x * v.x + v.y * v.y + v.z * v.z + v.w * v.w;
        #pragma unroll
        for (int off = 16; off > 0; off >>= 1) p += __shfl_xor(p, off, 64);
        if (d4 == 0) y2[row] = p + SBIAS;
    } else if (t < XN4 + YN4 + 176) {
        y2[M_PTS + (t - XN4 - YN4)] = FLT_MAX;   // pad tiles: never selected
    }
}

// ---------------------------------------------------------------------------
// Filter: fp8 e4m3 16x16x128 scaled-MFMA (unit scales), TWO query-sets per
// wave, C = y2+SBIAS splat, per-lane-class top-4 via min+3 med3 (5 VALU/score
// = proven instruction floor, R10-R15 law: wall ~3.35us per M wave-VALU).
// R6: launch_bounds BACK to (256,4). R5's (256,8) forced the allocator to
// 32 VGPRs -> full spill of the ~64-reg working set -> 1.8 GB scratch
// traffic, 786 us. With (256,4) the allocator uses ~52 VGPR (proven R1/R4);
// 52 <= 64 so the HW can still co-schedule 8 blocks/CU (LDS 16.9 KB allows
// 9). Occupancy comes from actual resources, not the bound.
// ---------------------------------------------------------------------------
__global__ __launch_bounds__(256, 4) void knn_filter(
    const u32* __restrict__ xb8, const u32* __restrict__ yt8,
    const float* __restrict__ y2, u32* __restrict__ ckey) {
    const int lane = threadIdx.x & 63;
    const int wid  = threadIdx.x >> 6;      // wave 0..3
    const int g    = lane >> 4;             // k-group 0..3
    const int nrow = lane & 15;             // point-in-tile (B col / C col)
    const int chunk = blockIdx.x;           // 0..31
    const int qb    = blockIdx.y;
    const int qw = qb * QPB + wid * 32;

    // A fragments: 2 query-sets, 8 dwords each (32 fp8 = k-slice 32g..32g+31)
    i32x8 a[2];
    #pragma unroll
    for (int s = 0; s < 2; ++s)
        a[s] = *(const i32x8*)(xb8 + (size_t)(qw + s * 16 + nrow) * 32 + g * 8);

    float ts[8][TPL];
    #pragma unroll
    for (int r = 0; r < 8; ++r)
        #pragma unroll
        for (int l = 0; l < TPL; ++l) ts[r][l] = FLT_MAX;

    const u32* ytp = yt8 + (size_t)chunk * TPC * 512 + lane * 8;
    const float* y2p = y2 + chunk * TPC * 16 + nrow;

    // prefetch tile 0 (R4: measured neutral, kept -- zero cost)
    i32x8 b = *(const i32x8*)(ytp);
    float y2n = y2p[0];

    #pragma unroll 2
    for (int t = 0; t < TPC; ++t) {
        int tn = (t + 1 < TPC) ? t + 1 : t;
        i32x8 bn = *(const i32x8*)(ytp + (size_t)tn * 512);
        float y2nn = y2p[tn * 16];

        f32x4 cq = {y2n, y2n, y2n, y2n};    // y2+SBIAS pre-loaded into C
        f32x4 d0 = __builtin_amdgcn_mfma_scale_f32_16x16x128_f8f6f4(
            a[0], b, cq, 0, 0, 0, 0x7F7F7F7F, 0, 0x7F7F7F7F);
        f32x4 d1 = __builtin_amdgcn_mfma_scale_f32_16x16x128_f8f6f4(
            a[1], b, cq, 0, 0, 0, 0x7F7F7F7F, 0, 0x7F7F7F7F);
        u32 rel = (u32)(t * 16) | (u32)nrow;          // < 1568, 12 bits
        #pragma unroll
        for (int i = 0; i < 4; ++i) {
            float key = __uint_as_float((__float_as_uint(d0[i]) & 0xFFFFF000u) | rel);
            float o0 = ts[i][0], o1 = ts[i][1], o2 = ts[i][2];
            ts[i][0] = fminf(o0, key);
            ts[i][1] = __builtin_amdgcn_fmed3f(key, o0, o1);
            ts[i][2] = __builtin_amdgcn_fmed3f(key, o1, o2);
            ts[i][3] = __builtin_amdgcn_fmed3f(key, o2, ts[i][3]);
        }
        #pragma unroll
        for (int i = 0; i < 4; ++i) {
            float key = __uint_as_float((__float_as_uint(d1[i]) & 0xFFFFF000u) | rel);
            float o0 = ts[4 + i][0], o1 = ts[4 + i][1], o2 = ts[4 + i][2];
            ts[4 + i][0] = fminf(o0, key);
            ts[4 + i][1] = __builtin_amdgcn_fmed3f(key, o0, o1);
            ts[4 + i][2] = __builtin_amdgcn_fmed3f(key, o1, o2);
            ts[4 + i][3] = __builtin_amdgcn_fmed3f(key, o2, ts[4 + i][3]);
        }
        b = bn;
        y2n = y2nn;
    }

    // ---- merge 16 lane-classes -> per-query sorted top-8, TWO PASSES ----
    // (pass s handles query-set s of every wave: 64 queries; LDS = 16.6 KB.)
    __shared__ u32 smem[64 * 65];           // 16640 B
    #pragma unroll
    for (int s = 0; s < 2; ++s) {
        if (s) __syncthreads();             // pass-0 reads done before reuse
        #pragma unroll
        for (int r = 0; r < 4; ++r) {
            int qh = wid * 16 + g * 4 + r;  // 0..63
            #pragma unroll
            for (int l = 0; l < TPL; ++l)
                smem[qh * 65 + nrow * TPL + l] = __float_as_uint(ts[s * 4 + r][l]);
        }
        __syncthreads();
        if (threadIdx.x < 64) {
            int qh = threadIdx.x;
            float bs[CPC];
            #pragma unroll
            for (int i = 0; i < CPC; ++i) bs[i] = FLT_MAX;
            for (int e = 0; e < 16 * TPL; ++e) {   // stride-65: conflict-free
                float f = __uint_as_float(smem[qh * 65 + e]);
                #pragma unroll
                for (int q2 = 0; q2 < CPC; ++q2) {
                    float mn = fminf(bs[q2], f);
                    f = fmaxf(bs[q2], f);
                    bs[q2] = mn;
                }
            }
            int gq = qb * QPB + (qh >> 4) * 32 + s * 16 + (qh & 15);
            u32* dst = ckey + ((size_t)gq * NCHUNK + chunk) * CPC;
            #pragma unroll
            for (int i = 0; i < CPC; ++i) dst[i] = __float_as_uint(bs[i]);
        }
    }
}

// ---------------------------------------------------------------------------
// Finalize: 8 queries/block, half-wave per query. NCAND 256, NSEL 48.
//  1. parallel exact-rank select of approx-top-48 from 256 keys (u32 compare
//     valid: keys positive via SBIAS; position tie-break -> unique ranks).
//  2. exact fp64 rescore, coalesced: half-wave does one candidate at a time,
//     32 lanes x float4 = 512B coalesced row load + butterfly reduce.
//  3. parallel top-10: each sub-lane ranks its (<=2) candidates among the 48
//     by (score,idx); rank<10 -> write LABEL. Ties -> LARGEST label.
// ---------------------------------------------------------------------------
__global__ __launch_bounds__(256) void knn_finalize(
    const u32* __restrict__ ckey, const float* __restrict__ x,
    const float* __restrict__ y, const int* __restrict__ labels,
    int* __restrict__ out) {
    const int lane = threadIdx.x & 63;
    const int wid  = threadIdx.x >> 6;
    const int qbase = blockIdx.x * 8;
    const int ql = wid * 2 + (lane >> 5);   // query-in-block 0..7
    const int sl = lane & 31;               // sub-lane in half-wave

    __shared__ u32 skey[8][NCAND];          // 8 KB
    __shared__ int sidx[8][NSEL];
    __shared__ double sex[8][NSEL];
    __shared__ int slab[8][KNN];

    for (int i = threadIdx.x; i < 8 * NCAND; i += 256)
        skey[i >> 8][i & 255] = ckey[(size_t)(qbase + (i >> 8)) * NCAND + (i & 255)];
    __syncthreads();

    // 1. parallel rank select: 8 candidates per sub-lane, one kj read per j
    {
        u32 ke[8];
        int rank[8];
        #pragma unroll
        for (int r0 = 0; r0 < 8; ++r0) {
            ke[r0] = skey[ql][r0 * 32 + sl];
            rank[r0] = 0;
        }
        for (int j = 0; j < NCAND; ++j) {
            u32 kj = skey[ql][j];
            #pragma unroll
            for (int r0 = 0; r0 < 8; ++r0)
                rank[r0] += (kj < ke[r0] || (kj == ke[r0] && j < r0 * 32 + sl)) ? 1 : 0;
        }
        #pragma unroll
        for (int r0 = 0; r0 < 8; ++r0) {
            if (rank[r0] < NSEL) {
                int e = r0 * 32 + sl;
                sidx[ql][rank[r0]] = (e >> 3) * (TPC * 16) + (int)(ke[r0] & 0xFFFu);
            }
        }
    }
    __syncthreads();

    // 2. exact fp64 rescore, coalesced per-candidate (half-wave cooperative)
    {
        const float4* xr = (const float4*)(x + (size_t)(qbase + ql) * DIM);
        float4 xv = xr[sl];                 // query row staged once, coalesced
        for (int c = 0; c < NSEL; ++c) {
            int idx = sidx[ql][c];          // LDS broadcast (uniform per half)
            const float4* yr = (const float4*)(y + (size_t)idx * DIM);
            float4 yv = yr[sl];             // 32 lanes x 16B = 512B coalesced
            double dy = 0.0, dx = 0.0;
            dy = fma((double)yv.x, (double)yv.x, dy);
            dy = fma((double)yv.y, (double)yv.y, dy);
            dy = fma((double)yv.z, (double)yv.z, dy);
            dy = fma((double)yv.w, (double)yv.w, dy);
            dx = fma((double)xv.x, (double)yv.x, dx);
            dx = fma((double)xv.y, (double)yv.y, dx);
            dx = fma((double)xv.z, (double)yv.z, dx);
            dx = fma((double)xv.w, (double)yv.w, dx);
            double part = fma(-2.0, dx, dy);
            #pragma unroll
            for (int off = 16; off > 0; off >>= 1)
                part += __shfl_xor(part, off, 64);   // stays within 32-half
            if (sl == 0) sex[ql][c] = part;
        }
    }
    __syncthreads();

    // 3. parallel top-10: rank candidates among the 48 by (score, idx)
    for (int c = sl; c < NSEL; c += 32) {
        int mi = sidx[ql][c];
        double s = sex[ql][c];
        int cnt = 0;
        #pragma unroll
        for (int j = 0; j < NSEL; ++j) {
            double sj = sex[ql][j];
            cnt += (sj < s || (sj == s && sidx[ql][j] < mi)) ? 1 : 0;
        }
        if (cnt < KNN) slab[ql][cnt] = labels[mi];
    }
    __syncthreads();

    if (sl == 0) {
        int lab[KNN];
        #pragma unroll
        for (int i = 0; i < KNN; ++i) lab[i] = slab[ql][i];
        int bestc = 0, bestn = -1;
        #pragma unroll
        for (int c = 0; c < NCLS; ++c) {
            int n = 0;
            #pragma unroll
            for (int i = 0; i < KNN; ++i) n += (lab[i] == c) ? 1 : 0;
            if (n >= bestn) { bestn = n; bestc = c; }   // >= : ties -> larger label
        }
        out[qbase + ql] = bestc;
    }
}

// ---------------------------------------------------------------------------
extern "C" void kernel_launch(void* const* d_in, const int* in_sizes, int n_in,
                              void* d_out, int out_size, void* d_ws, size_t ws_size,
                              hipStream_t stream) {
    const float* x      = (const float*)d_in[0];
    const float* y      = (const float*)d_in[1];
    const int*   labels = (const int*)d_in[2];
    // d_in[3] is k == 10, baked in.

    char* ws = (char*)d_ws;
    size_t off = 0;
    u32* xb8 = (u32*)(ws + off);    off += (size_t)N_Q * DIM;            //  1.05 MB
    u32* yt8 = (u32*)(ws + off);    off += (size_t)NCHUNK * TPC * 2048;  //  6.42 MB
    float* y2 = (float*)(ws + off); off += (size_t)NCHUNK * TPC * 16 * 4;//  0.20 MB
    u32* ckey = (u32*)(ws + off);   off += (size_t)N_Q * NCAND * 4;      //  8.39 MB
    int* out = (int*)d_out;

    prep_kernel<<<(XN4 + YN4 + 176 + 255) / 256, 256, 0, stream>>>(
        (const float4*)x, (const float4*)y, xb8, yt8, y2);
    knn_filter<<<dim3(NCHUNK, N_Q / QPB), 256, 0, stream>>>(xb8, yt8, y2, ckey);
    knn_finalize<<<N_Q / 8, 256, 0, stream>>>(ckey, x, y, labels, out);
}

// Round 11
// 225.774 us; speedup vs baseline: 4.3664x; 1.4850x over previous
//
#include <hip/hip_runtime.h>
#include <float.h>
#include <limits.h>

#define N_Q 8192
#define M_PTS 50000
#define DIM 128
#define KNN 10
#define NCLS 10
#define NCHUNK 16          // PROVEN: 16 chunks x 196 tiles (R8: 32-chunk was a net loss)
#define TPC 196            // tiles per chunk (uniform, compile-time)
#define CPC 8              // candidates kept per (query, chunk)
#define NCAND (NCHUNK*CPC) // 128 candidates per query
#define NSEL 24            // exact-rescored candidates (24 = proven margin; 20 failed R16)
#define TPL 4              // per-lane-class top depth (16 streams/chunk: safe)
#define QPB 128            // queries per block (4 waves x 32)
#define SBIAS 256.0f       // pre-added to y2: keys positive -> u32 order == float order
#define XN4 (N_Q*DIM/4)    // 262144 float4 in x
#define YN4 (M_PTS*DIM/4)  // 1600000 float4 in y

typedef __attribute__((ext_vector_type(8))) int i32x8;
typedef __attribute__((ext_vector_type(4))) float f32x4;
typedef unsigned int u32;

// ---------------------------------------------------------------------------
// fp32 -> e4m3 via the HW packed converter.
// ---------------------------------------------------------------------------
__device__ __forceinline__ u32 pack4_e4m3(float4 v, float sc) {
    u32 w = 0;
    w = __builtin_amdgcn_cvt_pk_fp8_f32(sc * v.x, sc * v.y, w, false);
    w = __builtin_amdgcn_cvt_pk_fp8_f32(sc * v.z, sc * v.w, w, true);
    return w;
}

// ---------------------------------------------------------------------------
// Prep (coalesced reads): xb8 = e4m3(-2x) row-major; yt8 = e4m3(y) tile
// records (2 KB/tile, slot l = g*16+nr); y2 = ||y||^2 + SBIAS;
// pads 50000..50175 = FLT_MAX.
// ---------------------------------------------------------------------------
__global__ __launch_bounds__(256) void prep_kernel(
    const float4* __restrict__ x4, const float4* __restrict__ y4,
    u32* __restrict__ xb8, u32* __restrict__ yt8, float* __restrict__ y2) {
    int t = blockIdx.x * 256 + threadIdx.x;
    if (t < XN4) {
        xb8[t] = pack4_e4m3(x4[t], -2.0f);  // row-major: u32 idx == t
    } else if (t < XN4 + YN4) {
        int j = t - XN4;                    // float4 index into y
        int row = j >> 5;                   // point 0..49999
        int d4  = j & 31;                   // which float4 of the row
        float4 v = y4[j];
        u32 w = pack4_e4m3(v, 1.0f);
        int T = row >> 4, nr = row & 15;
        int g2 = d4 >> 3, s = d4 & 7;
        yt8[(size_t)T * 512 + (g2 * 16 + nr) * 8 + s] = w;
        float p = v.x * v.x + v.y * v.y + v.z * v.z + v.w * v.w;
        #pragma unroll
        for (int off = 16; off > 0; off >>= 1) p += __shfl_xor(p, off, 64);
        if (d4 == 0) y2[row] = p + SBIAS;
    } else if (t < XN4 + YN4 + 176) {
        y2[M_PTS + (t - XN4 - YN4)] = FLT_MAX;   // pad tiles: never selected
    }
}

// ---------------------------------------------------------------------------
// Filter = R1/R4 proven structure (131 us): fp8 e4m3 16x16x128 scaled-MFMA
// (unit scales), TWO query-sets per wave, C = y2+SBIAS splat, per-lane-class
// top-4 via min+3 med3 (5 VALU/score = instruction floor; wall ~3.35us per M
// wave-VALU-insts). R8 falsified the occupancy lever: 41.6% occ gave the
// same 74% VALUBusy as 31% -- the filter is issue-plateau-bound, config
// reverted to the proven 16-chunk / one-pass merge / (256,4).
// ---------------------------------------------------------------------------
__global__ __launch_bounds__(256, 4) void knn_filter(
    const u32* __restrict__ xb8, const u32* __restrict__ yt8,
    const float* __restrict__ y2, u32* __restrict__ ckey) {
    const int lane = threadIdx.x & 63;
    const int wid  = threadIdx.x >> 6;      // wave 0..3
    const int g    = lane >> 4;             // k-group 0..3
    const int nrow = lane & 15;             // point-in-tile (B col / C col)
    const int chunk = blockIdx.x;           // gridDim.x=16 -> XCD = chunk%8
    const int qb    = blockIdx.y;
    const int qw = qb * QPB + wid * 32;

    // A fragments: 2 query-sets, 8 dwords each (32 fp8 = k-slice 32g..32g+31)
    i32x8 a[2];
    #pragma unroll
    for (int s = 0; s < 2; ++s)
        a[s] = *(const i32x8*)(xb8 + (size_t)(qw + s * 16 + nrow) * 32 + g * 8);

    float ts[8][TPL];
    #pragma unroll
    for (int r = 0; r < 8; ++r)
        #pragma unroll
        for (int l = 0; l < TPL; ++l) ts[r][l] = FLT_MAX;

    const u32* ytp = yt8 + (size_t)chunk * TPC * 512 + lane * 8;
    const float* y2p = y2 + chunk * TPC * 16 + nrow;

    // prefetch tile 0 (R4: measured neutral, kept -- zero cost)
    i32x8 b = *(const i32x8*)(ytp);
    float y2n = y2p[0];

    #pragma unroll 2
    for (int t = 0; t < TPC; ++t) {
        int tn = (t + 1 < TPC) ? t + 1 : t;
        i32x8 bn = *(const i32x8*)(ytp + (size_t)tn * 512);
        float y2nn = y2p[tn * 16];

        f32x4 cq = {y2n, y2n, y2n, y2n};    // y2+SBIAS pre-loaded into C
        f32x4 d0 = __builtin_amdgcn_mfma_scale_f32_16x16x128_f8f6f4(
            a[0], b, cq, 0, 0, 0, 0x7F7F7F7F, 0, 0x7F7F7F7F);
        f32x4 d1 = __builtin_amdgcn_mfma_scale_f32_16x16x128_f8f6f4(
            a[1], b, cq, 0, 0, 0, 0x7F7F7F7F, 0, 0x7F7F7F7F);
        u32 rel = (u32)(t * 16) | (u32)nrow;          // < 3136, 12 bits
        #pragma unroll
        for (int i = 0; i < 4; ++i) {
            float key = __uint_as_float((__float_as_uint(d0[i]) & 0xFFFFF000u) | rel);
            float o0 = ts[i][0], o1 = ts[i][1], o2 = ts[i][2];
            ts[i][0] = fminf(o0, key);
            ts[i][1] = __builtin_amdgcn_fmed3f(key, o0, o1);
            ts[i][2] = __builtin_amdgcn_fmed3f(key, o1, o2);
            ts[i][3] = __builtin_amdgcn_fmed3f(key, o2, ts[i][3]);
        }
        #pragma unroll
        for (int i = 0; i < 4; ++i) {
            float key = __uint_as_float((__float_as_uint(d1[i]) & 0xFFFFF000u) | rel);
            float o0 = ts[4 + i][0], o1 = ts[4 + i][1], o2 = ts[4 + i][2];
            ts[4 + i][0] = fminf(o0, key);
            ts[4 + i][1] = __builtin_amdgcn_fmed3f(key, o0, o1);
            ts[4 + i][2] = __builtin_amdgcn_fmed3f(key, o1, o2);
            ts[4 + i][3] = __builtin_amdgcn_fmed3f(key, o2, ts[4 + i][3]);
        }
        b = bn;
        y2n = y2nn;
    }

    // ---- merge 16 lane-classes -> per-query sorted top-8 ----
    __shared__ u32 smem[QPB * 65];          // 33280 B
    #pragma unroll
    for (int s = 0; s < 2; ++s)
        #pragma unroll
        for (int r = 0; r < 4; ++r) {
            int ql = wid * 32 + s * 16 + g * 4 + r;
            #pragma unroll
            for (int l = 0; l < TPL; ++l)
                smem[ql * 65 + nrow * TPL + l] = __float_as_uint(ts[s * 4 + r][l]);
        }
    __syncthreads();
    if (threadIdx.x < QPB) {
        int ql = threadIdx.x;
        float bs[CPC];
        #pragma unroll
        for (int i = 0; i < CPC; ++i) bs[i] = FLT_MAX;
        for (int e = 0; e < 16 * TPL; ++e) {      // stride-65: conflict-free
            float f = __uint_as_float(smem[ql * 65 + e]);
            #pragma unroll
            for (int q2 = 0; q2 < CPC; ++q2) {
                float mn = fminf(bs[q2], f);
                f = fmaxf(bs[q2], f);
                bs[q2] = mn;
            }
        }
        u32* dst = ckey + ((size_t)(qb * QPB + ql) * NCHUNK + chunk) * CPC;
        #pragma unroll
        for (int i = 0; i < CPC; ++i) dst[i] = __float_as_uint(bs[i]);
    }
}

// ---------------------------------------------------------------------------
// Finalize: 8 queries/block, half-wave per query. R8 counters (at 2x size):
// VALUBusy 47%, HBM 4.9%, MfmaUtil 0 -> latency/serialization-bound. R9
// attacks the two serial phases (identical semantics):
//  1. rank select with uint4 LDS reads: 32 vector loads (was 128 scalar).
//  2. rescore with TWO 16-lane groups per half-wave: candidates 2t/2t+1 in
//     flight together (12 serial iters, was 24), 32B/lane, rows still 512B
//     coalesced; 4-step butterfly per group. fp64 reassoc only (~1 ulp).
//  3. parallel top-10 (unchanged): rank among 24 by (score,idx), rank<10
//     writes LABEL. Class ties -> LARGEST label (reference reversed-argmax).
// ---------------------------------------------------------------------------
__global__ __launch_bounds__(256) void knn_finalize(
    const u32* __restrict__ ckey, const float* __restrict__ x,
    const float* __restrict__ y, const int* __restrict__ labels,
    int* __restrict__ out) {
    const int lane = threadIdx.x & 63;
    const int wid  = threadIdx.x >> 6;
    const int qbase = blockIdx.x * 8;
    const int ql = wid * 2 + (lane >> 5);   // query-in-block 0..7
    const int sl = lane & 31;               // sub-lane in half-wave

    __shared__ u32 skey[8][NCAND];
    __shared__ int sidx[8][NSEL];
    __shared__ double sex[8][NSEL];
    __shared__ int slab[8][KNN];

    for (int i = threadIdx.x; i < 8 * NCAND; i += 256)
        skey[i >> 7][i & 127] = ckey[(size_t)(qbase + (i >> 7)) * NCAND + (i & 127)];
    __syncthreads();

    // 1. parallel rank select, uint4-vectorized: 4 candidates per sub-lane
    {
        u32 ke[4];
        int rank[4];
        #pragma unroll
        for (int r0 = 0; r0 < 4; ++r0) {
            ke[r0] = skey[ql][r0 * 32 + sl];
            rank[r0] = 0;
        }
        const uint4* sk4 = (const uint4*)&skey[ql][0];   // 512B row, 16B aligned
        for (int j4 = 0; j4 < NCAND / 4; ++j4) {
            uint4 kv = sk4[j4];
            u32 kj[4] = {kv.x, kv.y, kv.z, kv.w};
            #pragma unroll
            for (int m = 0; m < 4; ++m) {
                int j = j4 * 4 + m;
                #pragma unroll
                for (int r0 = 0; r0 < 4; ++r0)
                    rank[r0] += (kj[m] < ke[r0] ||
                                 (kj[m] == ke[r0] && j < r0 * 32 + sl)) ? 1 : 0;
            }
        }
        #pragma unroll
        for (int r0 = 0; r0 < 4; ++r0) {
            if (rank[r0] < NSEL) {
                int e = r0 * 32 + sl;
                sidx[ql][rank[r0]] = (e >> 3) * (TPC * 16) + (int)(ke[r0] & 0xFFFu);
            }
        }
    }
    __syncthreads();

    // 2. exact fp64 rescore: two 16-lane groups, candidates 2t and 2t+1
    {
        const int grp = sl >> 4;            // 0 or 1: candidate parity
        const int d   = sl & 15;            // lane in group
        const float4* xr = (const float4*)(x + (size_t)(qbase + ql) * DIM);
        float4 xv0 = xr[2 * d], xv1 = xr[2 * d + 1];   // 32B of x per lane
        for (int t = 0; t < NSEL / 2; ++t) {
            int c = 2 * t + grp;
            int idx = sidx[ql][c];
            const float4* yr = (const float4*)(y + (size_t)idx * DIM);
            float4 yv0 = yr[2 * d], yv1 = yr[2 * d + 1];  // 16x32B = 512B row
            double dy0 = 0.0, dy1 = 0.0, dx0 = 0.0, dx1 = 0.0;
            dy0 = fma((double)yv0.x, (double)yv0.x, dy0);
            dy0 = fma((double)yv0.y, (double)yv0.y, dy0);
            dy0 = fma((double)yv0.z, (double)yv0.z, dy0);
            dy0 = fma((double)yv0.w, (double)yv0.w, dy0);
            dy1 = fma((double)yv1.x, (double)yv1.x, dy1);
            dy1 = fma((double)yv1.y, (double)yv1.y, dy1);
            dy1 = fma((double)yv1.z, (double)yv1.z, dy1);
            dy1 = fma((double)yv1.w, (double)yv1.w, dy1);
            dx0 = fma((double)xv0.x, (double)yv0.x, dx0);
            dx0 = fma((double)xv0.y, (double)yv0.y, dx0);
            dx0 = fma((double)xv0.z, (double)yv0.z, dx0);
            dx0 = fma((double)xv0.w, (double)yv0.w, dx0);
            dx1 = fma((double)xv1.x, (double)yv1.x, dx1);
            dx1 = fma((double)xv1.y, (double)yv1.y, dx1);
            dx1 = fma((double)xv1.z, (double)yv1.z, dx1);
            dx1 = fma((double)xv1.w, (double)yv1.w, dx1);
            double part = fma(-2.0, dx0 + dx1, dy0 + dy1);
            #pragma unroll
            for (int off = 8; off > 0; off >>= 1)
                part += __shfl_xor(part, off, 64);   // stays within 16-group
            if (d == 0) sex[ql][c] = part;
        }
    }
    __syncthreads();

    // 3. parallel top-10: rank my candidate among the 24 by (score, idx)
    int myidx = (sl < NSEL) ? sidx[ql][sl] : 0;
    if (sl < NSEL) {
        double s = sex[ql][sl];
        int cnt = 0;
        #pragma unroll
        for (int j = 0; j < NSEL; ++j) {
            double sj = sex[ql][j];
            cnt += (sj < s || (sj == s && sidx[ql][j] < myidx)) ? 1 : 0;
        }
        if (cnt < KNN) slab[ql][cnt] = labels[myidx];
    }
    __syncthreads();

    if (sl == 0) {
        int lab[KNN];
        #pragma unroll
        for (int i = 0; i < KNN; ++i) lab[i] = slab[ql][i];
        int bestc = 0, bestn = -1;
        #pragma unroll
        for (int c = 0; c < NCLS; ++c) {
            int n = 0;
            #pragma unroll
            for (int i = 0; i < KNN; ++i) n += (lab[i] == c) ? 1 : 0;
            if (n >= bestn) { bestn = n; bestc = c; }   // >= : ties -> larger label
        }
        out[qbase + ql] = bestc;
    }
}

// ---------------------------------------------------------------------------
extern "C" void kernel_launch(void* const* d_in, const int* in_sizes, int n_in,
                              void* d_out, int out_size, void* d_ws, size_t ws_size,
                              hipStream_t stream) {
    const float* x      = (const float*)d_in[0];
    const float* y      = (const float*)d_in[1];
    const int*   labels = (const int*)d_in[2];
    // d_in[3] is k == 10, baked in.

    char* ws = (char*)d_ws;
    size_t off = 0;
    u32* xb8 = (u32*)(ws + off);    off += (size_t)N_Q * DIM;            //  1.05 MB
    u32* yt8 = (u32*)(ws + off);    off += (size_t)NCHUNK * TPC * 2048;  //  6.42 MB
    float* y2 = (float*)(ws + off); off += (size_t)NCHUNK * TPC * 16 * 4;//  0.20 MB
    u32* ckey = (u32*)(ws + off);   off += (size_t)N_Q * NCAND * 4;      //  4.19 MB
    int* out = (int*)d_out;

    prep_kernel<<<(XN4 + YN4 + 176 + 255) / 256, 256, 0, stream>>>(
        (const float4*)x, (const float4*)y, xb8, yt8, y2);
    knn_filter<<<dim3(NCHUNK, N_Q / QPB), 256, 0, stream>>>(xb8, yt8, y2, ckey);
    knn_finalize<<<N_Q / 8, 256, 0, stream>>>(ckey, x, y, labels, out);
}

// Round 14
// 221.907 us; speedup vs baseline: 4.4425x; 1.0174x over previous
//
#include <hip/hip_runtime.h>
#include <float.h>
#include <limits.h>

#define N_Q 8192
#define M_PTS 50000
#define DIM 128
#define KNN 10
#define NCLS 10
#define NCHUNK 16          // PROVEN: 16 chunks x 196 tiles (R8: 32-chunk was a net loss)
#define TPC 196            // tiles per chunk (uniform, compile-time)
#define CPC 8              // candidates kept per (query, chunk)
#define NCAND (NCHUNK*CPC) // 128 candidates per query
#define NSEL 24            // exact-rescored candidates (24 = proven margin; 20 failed R16)
#define TPL 4              // per-lane-class top depth (16 streams/chunk: safe)
#define QPB 128            // queries per block (4 waves x 32)
#define SBIAS 256.0f       // pre-added to y2: keys positive -> u32 order == float order
#define XN4 (N_Q*DIM/4)    // 262144 float4 in x
#define YN4 (M_PTS*DIM/4)  // 1600000 float4 in y

typedef __attribute__((ext_vector_type(8))) int i32x8;
typedef __attribute__((ext_vector_type(4))) float f32x4;
typedef unsigned int u32;

// ---------------------------------------------------------------------------
// fp32 -> e4m3 via the HW packed converter.
// ---------------------------------------------------------------------------
__device__ __forceinline__ u32 pack4_e4m3(float4 v, float sc) {
    u32 w = 0;
    w = __builtin_amdgcn_cvt_pk_fp8_f32(sc * v.x, sc * v.y, w, false);
    w = __builtin_amdgcn_cvt_pk_fp8_f32(sc * v.z, sc * v.w, w, true);
    return w;
}

// ---------------------------------------------------------------------------
// Prep (coalesced reads): xb8 = e4m3(-2x) row-major; yt8 = e4m3(y) tile
// records (2 KB/tile, slot l = g*16+nr); y2 = ||y||^2 + SBIAS;
// pads 50000..50175 = FLT_MAX.
// ---------------------------------------------------------------------------
__global__ __launch_bounds__(256) void prep_kernel(
    const float4* __restrict__ x4, const float4* __restrict__ y4,
    u32* __restrict__ xb8, u32* __restrict__ yt8, float* __restrict__ y2) {
    int t = blockIdx.x * 256 + threadIdx.x;
    if (t < XN4) {
        xb8[t] = pack4_e4m3(x4[t], -2.0f);  // row-major: u32 idx == t
    } else if (t < XN4 + YN4) {
        int j = t - XN4;                    // float4 index into y
        int row = j >> 5;                   // point 0..49999
        int d4  = j & 31;                   // which float4 of the row
        float4 v = y4[j];
        u32 w = pack4_e4m3(v, 1.0f);
        int T = row >> 4, nr = row & 15;
        int g2 = d4 >> 3, s = d4 & 7;
        yt8[(size_t)T * 512 + (g2 * 16 + nr) * 8 + s] = w;
        float p = v.x * v.x + v.y * v.y + v.z * v.z + v.w * v.w;
        #pragma unroll
        for (int off = 16; off > 0; off >>= 1) p += __shfl_xor(p, off, 64);
        if (d4 == 0) y2[row] = p + SBIAS;
    } else if (t < XN4 + YN4 + 176) {
        y2[M_PTS + (t - XN4 - YN4)] = FLT_MAX;   // pad tiles: never selected
    }
}

// ---------------------------------------------------------------------------
// Filter = R1/R4 proven structure (131 us): fp8 e4m3 16x16x128 scaled-MFMA
// (unit scales), TWO query-sets per wave, C = y2+SBIAS splat, per-lane-class
// top-4 via min+3 med3 (5 VALU/score = instruction floor; wall ~3.35us per M
// wave-VALU-insts -- static count 38.5M matches). R8 falsified the occupancy
// lever: more waves, same busy%. (VALUBusy counter over-reads: gfx94x formula
// fallback.) BYTE-IDENTICAL to the R11-measured 131 us kernel.
// ---------------------------------------------------------------------------
__global__ __launch_bounds__(256, 4) void knn_filter(
    const u32* __restrict__ xb8, const u32* __restrict__ yt8,
    const float* __restrict__ y2, u32* __restrict__ ckey) {
    const int lane = threadIdx.x & 63;
    const int wid  = threadIdx.x >> 6;      // wave 0..3
    const int g    = lane >> 4;             // k-group 0..3
    const int nrow = lane & 15;             // point-in-tile (B col / C col)
    const int chunk = blockIdx.x;           // gridDim.x=16 -> XCD = chunk%8
    const int qb    = blockIdx.y;
    const int qw = qb * QPB + wid * 32;

    // A fragments: 2 query-sets, 8 dwords each (32 fp8 = k-slice 32g..32g+31)
    i32x8 a[2];
    #pragma unroll
    for (int s = 0; s < 2; ++s)
        a[s] = *(const i32x8*)(xb8 + (size_t)(qw + s * 16 + nrow) * 32 + g * 8);

    float ts[8][TPL];
    #pragma unroll
    for (int r = 0; r < 8; ++r)
        #pragma unroll
        for (int l = 0; l < TPL; ++l) ts[r][l] = FLT_MAX;

    const u32* ytp = yt8 + (size_t)chunk * TPC * 512 + lane * 8;
    const float* y2p = y2 + chunk * TPC * 16 + nrow;

    // prefetch tile 0 (R4: measured neutral, kept -- zero cost)
    i32x8 b = *(const i32x8*)(ytp);
    float y2n = y2p[0];

    #pragma unroll 2
    for (int t = 0; t < TPC; ++t) {
        int tn = (t + 1 < TPC) ? t + 1 : t;
        i32x8 bn = *(const i32x8*)(ytp + (size_t)tn * 512);
        float y2nn = y2p[tn * 16];

        f32x4 cq = {y2n, y2n, y2n, y2n};    // y2+SBIAS pre-loaded into C
        f32x4 d0 = __builtin_amdgcn_mfma_scale_f32_16x16x128_f8f6f4(
            a[0], b, cq, 0, 0, 0, 0x7F7F7F7F, 0, 0x7F7F7F7F);
        f32x4 d1 = __builtin_amdgcn_mfma_scale_f32_16x16x128_f8f6f4(
            a[1], b, cq, 0, 0, 0, 0x7F7F7F7F, 0, 0x7F7F7F7F);
        u32 rel = (u32)(t * 16) | (u32)nrow;          // < 3136, 12 bits
        #pragma unroll
        for (int i = 0; i < 4; ++i) {
            float key = __uint_as_float((__float_as_uint(d0[i]) & 0xFFFFF000u) | rel);
            float o0 = ts[i][0], o1 = ts[i][1], o2 = ts[i][2];
            ts[i][0] = fminf(o0, key);
            ts[i][1] = __builtin_amdgcn_fmed3f(key, o0, o1);
            ts[i][2] = __builtin_amdgcn_fmed3f(key, o1, o2);
            ts[i][3] = __builtin_amdgcn_fmed3f(key, o2, ts[i][3]);
        }
        #pragma unroll
        for (int i = 0; i < 4; ++i) {
            float key = __uint_as_float((__float_as_uint(d1[i]) & 0xFFFFF000u) | rel);
            float o0 = ts[4 + i][0], o1 = ts[4 + i][1], o2 = ts[4 + i][2];
            ts[4 + i][0] = fminf(o0, key);
            ts[4 + i][1] = __builtin_amdgcn_fmed3f(key, o0, o1);
            ts[4 + i][2] = __builtin_amdgcn_fmed3f(key, o1, o2);
            ts[4 + i][3] = __builtin_amdgcn_fmed3f(key, o2, ts[4 + i][3]);
        }
        b = bn;
        y2n = y2nn;
    }

    // ---- merge 16 lane-classes -> per-query sorted top-8 ----
    __shared__ u32 smem[QPB * 65];          // 33280 B
    #pragma unroll
    for (int s = 0; s < 2; ++s)
        #pragma unroll
        for (int r = 0; r < 4; ++r) {
            int ql = wid * 32 + s * 16 + g * 4 + r;
            #pragma unroll
            for (int l = 0; l < TPL; ++l)
                smem[ql * 65 + nrow * TPL + l] = __float_as_uint(ts[s * 4 + r][l]);
        }
    __syncthreads();
    if (threadIdx.x < QPB) {
        int ql = threadIdx.x;
        float bs[CPC];
        #pragma unroll
        for (int i = 0; i < CPC; ++i) bs[i] = FLT_MAX;
        for (int e = 0; e < 16 * TPL; ++e) {      // stride-65: conflict-free
            float f = __uint_as_float(smem[ql * 65 + e]);
            #pragma unroll
            for (int q2 = 0; q2 < CPC; ++q2) {
                float mn = fminf(bs[q2], f);
                f = fmaxf(bs[q2], f);
                bs[q2] = mn;
            }
        }
        u32* dst = ckey + ((size_t)(qb * QPB + ql) * NCHUNK + chunk) * CPC;
        #pragma unroll
        for (int i = 0; i < CPC; ++i) dst[i] = __float_as_uint(bs[i]);
    }
}

// ---------------------------------------------------------------------------
// Finalize: 8 queries/block, half-wave per query.
// R8 direct measurement (2x cfg): 142 us, FETCH 54MB @ 390 GB/s, VALUBusy
// 47% -> LATENCY-bound scattered gather; R11's serial restructure was
// neutral (no MLP change). R12: rescore MLP attack -- 3 rounds x 8
// CONCURRENT candidates (4 lanes each, 8 independent coalesced float4 loads
// per lane, mapping k*4+d: each inst fetches 8 rows x 64B contiguous).
// In-flight 4KB/query/round (was 1KB); serial trips 12 -> 3.
//  1. rank select (R11 uint4 form, measured-correct).
//  3. parallel top-10 (unchanged). Ties -> LARGEST label.
// ---------------------------------------------------------------------------
__global__ __launch_bounds__(256) void knn_finalize(
    const u32* __restrict__ ckey, const float* __restrict__ x,
    const float* __restrict__ y, const int* __restrict__ labels,
    int* __restrict__ out) {
    const int lane = threadIdx.x & 63;
    const int wid  = threadIdx.x >> 6;
    const int qbase = blockIdx.x * 8;
    const int ql = wid * 2 + (lane >> 5);   // query-in-block 0..7
    const int sl = lane & 31;               // sub-lane in half-wave

    __shared__ u32 skey[8][NCAND];
    __shared__ int sidx[8][NSEL];
    __shared__ double sex[8][NSEL];
    __shared__ int slab[8][KNN];

    for (int i = threadIdx.x; i < 8 * NCAND; i += 256)
        skey[i >> 7][i & 127] = ckey[(size_t)(qbase + (i >> 7)) * NCAND + (i & 127)];
    __syncthreads();

    // 1. parallel rank select, uint4-vectorized: 4 candidates per sub-lane
    {
        u32 ke[4];
        int rank[4];
        #pragma unroll
        for (int r0 = 0; r0 < 4; ++r0) {
            ke[r0] = skey[ql][r0 * 32 + sl];
            rank[r0] = 0;
        }
        const uint4* sk4 = (const uint4*)&skey[ql][0];   // 512B row, 16B aligned
        for (int j4 = 0; j4 < NCAND / 4; ++j4) {
            uint4 kv = sk4[j4];
            u32 kj[4] = {kv.x, kv.y, kv.z, kv.w};
            #pragma unroll
            for (int m = 0; m < 4; ++m) {
                int j = j4 * 4 + m;
                #pragma unroll
                for (int r0 = 0; r0 < 4; ++r0)
                    rank[r0] += (kj[m] < ke[r0] ||
                                 (kj[m] == ke[r0] && j < r0 * 32 + sl)) ? 1 : 0;
            }
        }
        #pragma unroll
        for (int r0 = 0; r0 < 4; ++r0) {
            if (rank[r0] < NSEL) {
                int e = r0 * 32 + sl;
                sidx[ql][rank[r0]] = (e >> 3) * (TPC * 16) + (int)(ke[r0] & 0xFFFu);
            }
        }
    }
    __syncthreads();

    // 2. exact fp64 rescore: 3 rounds x 8 concurrent candidates, 4 lanes ea.
    {
        const int cir = sl >> 2;            // candidate-in-round 0..7
        const int d   = sl & 3;             // lane-in-quad
        const float4* xr = (const float4*)(x + (size_t)(qbase + ql) * DIM);
        float4 xv[8];
        #pragma unroll
        for (int k = 0; k < 8; ++k) xv[k] = xr[k * 4 + d];  // quad covers row
        #pragma unroll
        for (int r = 0; r < 3; ++r) {
            int c = r * 8 + cir;
            int idx = sidx[ql][c];
            const float4* yr = (const float4*)(y + (size_t)idx * DIM);
            float4 yv[8];
            #pragma unroll
            for (int k = 0; k < 8; ++k) yv[k] = yr[k * 4 + d];  // 8 indep loads
            double dy0 = 0.0, dy1 = 0.0, dx0 = 0.0, dx1 = 0.0;
            #pragma unroll
            for (int k = 0; k < 8; k += 2) {
                dy0 = fma((double)yv[k].x, (double)yv[k].x, dy0);
                dy0 = fma((double)yv[k].y, (double)yv[k].y, dy0);
                dy0 = fma((double)yv[k].z, (double)yv[k].z, dy0);
                dy0 = fma((double)yv[k].w, (double)yv[k].w, dy0);
                dx0 = fma((double)xv[k].x, (double)yv[k].x, dx0);
                dx0 = fma((double)xv[k].y, (double)yv[k].y, dx0);
                dx0 = fma((double)xv[k].z, (double)yv[k].z, dx0);
                dx0 = fma((double)xv[k].w, (double)yv[k].w, dx0);
                dy1 = fma((double)yv[k+1].x, (double)yv[k+1].x, dy1);
                dy1 = fma((double)yv[k+1].y, (double)yv[k+1].y, dy1);
                dy1 = fma((double)yv[k+1].z, (double)yv[k+1].z, dy1);
                dy1 = fma((double)yv[k+1].w, (double)yv[k+1].w, dy1);
                dx1 = fma((double)xv[k+1].x, (double)yv[k+1].x, dx1);
                dx1 = fma((double)xv[k+1].y, (double)yv[k+1].y, dx1);
                dx1 = fma((double)xv[k+1].z, (double)yv[k+1].z, dx1);
                dx1 = fma((double)xv[k+1].w, (double)yv[k+1].w, dx1);
            }
            double part = fma(-2.0, dx0 + dx1, dy0 + dy1);
            part += __shfl_xor(part, 1, 64);            // quad butterfly
            part += __shfl_xor(part, 2, 64);
            if (d == 0) sex[ql][c] = part;
        }
    }
    __syncthreads();

    // 3. parallel top-10: rank my candidate among the 24 by (score, idx)
    int myidx = (sl < NSEL) ? sidx[ql][sl] : 0;
    if (sl < NSEL) {
        double s = sex[ql][sl];
        int cnt = 0;
        #pragma unroll
        for (int j = 0; j < NSEL; ++j) {
            double sj = sex[ql][j];
            cnt += (sj < s || (sj == s && sidx[ql][j] < myidx)) ? 1 : 0;
        }
        if (cnt < KNN) slab[ql][cnt] = labels[myidx];
    }
    __syncthreads();

    if (sl == 0) {
        int lab[KNN];
        #pragma unroll
        for (int i = 0; i < KNN; ++i) lab[i] = slab[ql][i];
        int bestc = 0, bestn = -1;
        #pragma unroll
        for (int c = 0; c < NCLS; ++c) {
            int n = 0;
            #pragma unroll
            for (int i = 0; i < KNN; ++i) n += (lab[i] == c) ? 1 : 0;
            if (n >= bestn) { bestn = n; bestc = c; }   // >= : ties -> larger label
        }
        out[qbase + ql] = bestc;
    }
}

// ---------------------------------------------------------------------------
extern "C" void kernel_launch(void* const* d_in, const int* in_sizes, int n_in,
                              void* d_out, int out_size, void* d_ws, size_t ws_size,
                              hipStream_t stream) {
    const float* x      = (const float*)d_in[0];
    const float* y      = (const float*)d_in[1];
    const int*   labels = (const int*)d_in[2];
    // d_in[3] is k == 10, baked in.

    char* ws = (char*)d_ws;
    size_t off = 0;
    u32* xb8 = (u32*)(ws + off);    off += (size_t)N_Q * DIM;            //  1.05 MB
    u32* yt8 = (u32*)(ws + off);    off += (size_t)NCHUNK * TPC * 2048;  //  6.42 MB
    float* y2 = (float*)(ws + off); off += (size_t)NCHUNK * TPC * 16 * 4;//  0.20 MB
    u32* ckey = (u32*)(ws + off);   off += (size_t)N_Q * NCAND * 4;      //  4.19 MB
    int* out = (int*)d_out;

    prep_kernel<<<(XN4 + YN4 + 176 + 255) / 256, 256, 0, stream>>>(
        (const float4*)x, (const float4*)y, xb8, yt8, y2);
    knn_filter<<<dim3(NCHUNK, N_Q / QPB), 256, 0, stream>>>(xb8, yt8, y2, ckey);
    knn_finalize<<<N_Q / 8, 256, 0, stream>>>(ckey, x, y, labels, out);
}